// Round 2
// 160.282 us; speedup vs baseline: 1.0137x; 1.0137x over previous
//
#include <hip/hip_runtime.h>

#define S_LEN 2048
#define HID   768
#define NH    12
#define HD    64
#define BATCH 2
#define GK    768   // GEMM K dim
#define L2E   1.44269504088896340736f
#define QSCL  (0.125f * L2E)

typedef __attribute__((ext_vector_type(8))) short bf16x8;
typedef __attribute__((ext_vector_type(4))) float f32x4;
typedef __attribute__((ext_vector_type(4))) short s16x4;
typedef __attribute__((ext_vector_type(8))) short s16x8;

// fp32 -> bf16 RNE (prep only)
__device__ __forceinline__ unsigned short f2bf(float f) {
    union { float f; unsigned int u; } v; v.f = f;
    unsigned int r = v.u + 0x7fffu + ((v.u >> 16) & 1u);
    return (unsigned short)(r >> 16);
}
// fp32 -> bf16 round-half-up: 1 VALU + hi-half extract (<=1 ulp vs RNE)
__device__ __forceinline__ unsigned short f2bf_hu(float f) {
    union { float f; unsigned int u; } v; v.f = f;
    return (unsigned short)((v.u + 0x8000u) >> 16);
}

// two fp32 -> packed bf16 pair (RNE), 1 VALU. No builtin on gfx950 (m240);
// dword = [15:0]=bf16(a), [31:16]=bf16(b).
__device__ __forceinline__ unsigned int cvtpk(float a, float b) {
    unsigned int r;
    asm("v_cvt_pk_bf16_f32 %0, %1, %2" : "=v"(r) : "v"(a), "v"(b));
    return r;
}

// async global->LDS, 16B per lane, dest = wave-uniform base + lane*16
#define GLL16(gp, lp) __builtin_amdgcn_global_load_lds( \
    (const __attribute__((address_space(1))) unsigned int*)(gp), \
    (__attribute__((address_space(3))) unsigned int*)(lp), 16, 0, 0)

// XOR-swizzle (r8, kept): 16B chunk (row, c) lives at LDS chunk c ^ (row&7);
// applied via the per-lane *global source* pointer, zero per-tile cost.

// ---------------------------------------------------------------------------
// Merged prep: blocks [0,3072) convert X fp32->bf16; blocks [3072,4800)
// transpose+convert Wq|Wk|Wv -> Wt [2304][768]. Wq rows and later bq are
// pre-scaled by QSCL so the GEMM/attn never multiply by it.
// ---------------------------------------------------------------------------
__global__ __launch_bounds__(256) void prep_kernel(
    const float* __restrict__ X, const float* __restrict__ Wq,
    const float* __restrict__ Wk, const float* __restrict__ Wv,
    unsigned short* __restrict__ Xb, unsigned short* __restrict__ Wt) {
    __shared__ float T[32][33];
    int bid = blockIdx.x;
    if (bid < 3072) {
        int id = bid * 256 + threadIdx.x;   // one float4 per thread
        float4 v = ((const float4*)X)[id];
        s16x4 o; o[0] = (short)f2bf(v.x); o[1] = (short)f2bf(v.y);
        o[2] = (short)f2bf(v.z); o[3] = (short)f2bf(v.w);
        ((s16x4*)Xb)[id] = o;
        return;
    }
    int t2 = bid - 3072;
    int mat = t2 / 576, t = t2 % 576;
    int tk = t / 24, tn = t % 24;
    const float* W = (mat == 0) ? Wq : (mat == 1) ? Wk : Wv;
    const float scl = (mat == 0) ? QSCL : 1.0f;
    int r  = threadIdx.x >> 3;
    int c4 = (threadIdx.x & 7) * 4;
    float4 v = *(const float4*)&W[(size_t)(tk*32 + r) * GK + tn*32 + c4];
    T[c4+0][r] = v.x; T[c4+1][r] = v.y; T[c4+2][r] = v.z; T[c4+3][r] = v.w;
    __syncthreads();
    s16x4 o;
    o[0] = (short)f2bf(T[r][c4+0] * scl); o[1] = (short)f2bf(T[r][c4+1] * scl);
    o[2] = (short)f2bf(T[r][c4+2] * scl); o[3] = (short)f2bf(T[r][c4+3] * scl);
    *(s16x4*)&Wt[(size_t)(mat*768 + tn*32 + r) * GK + tk*32 + c4] = o;
}

// ---------------------------------------------------------------------------
// Fused QKV GEMM, bf16 MFMA 16x16x32, 128(M)x64(N) tile, BK=64, 1152 blocks.
// global_load_lds width=16 staging, XOR-swizzled LDS (r8).
// Q -> TRANSPOSED [B,H,64,S] (pre-scaled via Wt/bias), packed 8B stores.
// K -> [B,H,S,64] row-major (attn needs d-contiguous K fragments).
// V -> TRANSPOSED [B,H,64,S], packed 8B stores.
// ---------------------------------------------------------------------------
__global__ __launch_bounds__(256) void gemm_qkv(
    const unsigned short* __restrict__ Xb, const unsigned short* __restrict__ Wt,
    const float* __restrict__ bq, const float* __restrict__ bk,
    const float* __restrict__ bv,
    unsigned short* __restrict__ qb, unsigned short* __restrict__ kb,
    unsigned short* __restrict__ vb) {
    __shared__ __align__(16) unsigned short As[128][64];
    __shared__ __align__(16) unsigned short Bs[64][64];

    const int tid = threadIdx.x;
    const int bm = blockIdx.y * 128;
    const int bn = blockIdx.x * 64;
    const int w = tid >> 6, l = tid & 63, quad = l >> 4, lq = l & 15;
    const int wx = w & 1, wy = w >> 1;

    const int srow = l >> 3, schunk = ((l & 7) ^ (l >> 3)) * 8;
    const unsigned short* aga = Xb + (size_t)(bm + w*32 + srow) * GK + schunk;
    const unsigned short* bga = Wt + (size_t)(bn + w*16 + srow) * GK + schunk;

    const int c0 = ((quad)     ^ (lq & 7)) * 8;
    const int c1 = ((4 + quad) ^ (lq & 7)) * 8;

    f32x4 zero = {0.f, 0.f, 0.f, 0.f};
    f32x4 acc[4][2];
#pragma unroll
    for (int mi = 0; mi < 4; mi++)
#pragma unroll
        for (int ni = 0; ni < 2; ni++) acc[mi][ni] = zero;

    for (int k0 = 0; k0 < GK; k0 += 64) {
        __syncthreads();
#pragma unroll
        for (int i = 0; i < 4; i++)
            GLL16(aga + k0 + i*8*GK, &As[w*32 + i*8][0]);
#pragma unroll
        for (int i = 0; i < 2; i++)
            GLL16(bga + k0 + i*8*GK, &Bs[w*16 + i*8][0]);
        __syncthreads();
#pragma unroll
        for (int kh = 0; kh < 2; kh++) {
            const int cc = kh ? c1 : c0;
            bf16x8 a[4], b[2];
#pragma unroll
            for (int mi = 0; mi < 4; mi++)
                a[mi] = *(const bf16x8*)&As[wy*64 + mi*16 + lq][cc];
#pragma unroll
            for (int ni = 0; ni < 2; ni++)
                b[ni] = *(const bf16x8*)&Bs[wx*32 + ni*16 + lq][cc];
#pragma unroll
            for (int mi = 0; mi < 4; mi++)
#pragma unroll
                for (int ni = 0; ni < 2; ni++)
                    acc[mi][ni] = __builtin_amdgcn_mfma_f32_16x16x32_bf16(
                        a[mi], b[ni], acc[mi][ni], 0, 0, 0);
        }
    }

    const int mat = bn / 768;   // block never straddles matrices
    const float* bias = (mat == 0) ? bq : (mat == 1) ? bk : bv;
    const float bscl = (mat == 0) ? QSCL : 1.0f;
    const int nbase = bn % 768;
#pragma unroll
    for (int ni = 0; ni < 2; ni++) {
        int hn = nbase + wx*32 + ni*16 + lq;
        float bval = bias[hn] * bscl;
        int h = hn >> 6, d = hn & 63;
#pragma unroll
        for (int mi = 0; mi < 4; mi++) {
            int m0 = bm + wy*64 + mi*16 + quad*4;
            int b_ = m0 >> 11, s0 = m0 & 2047;
            if (mat != 1) {
                // transposed [B,H,d,S]: 4 consecutive s -> one 8B store
                unsigned short* outp = (mat == 0) ? qb : vb;
                s16x4 pk;
#pragma unroll
                for (int r = 0; r < 4; r++) pk[r] = (short)f2bf_hu(acc[mi][ni][r] + bval);
                *(s16x4*)&outp[((size_t)((b_*NH + h) * HD + d)) * S_LEN + s0] = pk;
            } else {
                size_t base = ((size_t)((b_*NH + h) * S_LEN + s0)) * HD + d;
#pragma unroll
                for (int r = 0; r < 4; r++)
                    kb[base + (size_t)r * HD] = f2bf_hu(acc[mi][ni][r] + bval);
            }
        }
    }
}

// ---------------------------------------------------------------------------
// MFMA flash attention v7b. Block = (b*h, 64 q-rows), 4 waves x 16 q-rows.
// - SWAPPED QK^T: st = mfma(K_frag, Q_frag) -> lane holds S^T[k][q=lq],
//   i.e. 4 consecutive k for ONE q-row. Softmax output is lane-contiguous:
//   8x v_cvt_pk_bf16_f32 + 4x ds_write_b64 (was 32 VALU + 16 ds_write_b16).
// - P store swizzle FIX (r1 bug): lane's g-th pair lives in logical chunk
//   (g*2 + quad/2); the XOR with (lq&7) must hit the FULL 3-bit chunk index,
//   computed per-g inside the unrolled loop (compile-time).
// - Ps [4][16][64] chunk-XOR swizzled exactly like Ks -> b128 read-back
//   reuses c0/c1; PV / ones-MFMA rowsum / epilogue unchanged.
// - Mask read per-quad as f32x4 (key-indexed after the swap).
// - XCD-aware block swizzle: 768 = 8 XCDs x 96; each XCD owns 3 heads'
//   q-blocks -> K/V (512KB/head) stays L2-local instead of 8x re-fetch.
// LDS = 16K Ks + 16K Vt + 8K Ps + 8K mask = 48 KB -> 3 blocks/CU.
// ---------------------------------------------------------------------------
__global__ __launch_bounds__(256) void attn_kernel(
    const unsigned short* __restrict__ Qtg, const unsigned short* __restrict__ Kg,
    const unsigned short* __restrict__ Vtg, const float* __restrict__ maskg,
    float* __restrict__ out) {
    __shared__ __align__(16) unsigned short Ks[2][64][64];
    __shared__ __align__(16) unsigned short Vt[2][64][64];
    __shared__ __align__(16) unsigned short Ps[4][16][64];
    __shared__ __align__(16) float mkL[S_LEN];

    const int tid = threadIdx.x;
    const int w = tid >> 6, l = tid & 63, quad = l >> 4, lq = l & 15;

    // bijective XCD swizzle (768 % 8 == 0): xcd = wgid % 8 owns virt
    // [xcd*96, xcd*96+96) = 3 consecutive bh
    const int wgid = blockIdx.y * gridDim.x + blockIdx.x;
    const int virt = (wgid & 7) * 96 + (wgid >> 3);
    const int bh = virt >> 5;
    const int q0 = (virt & 31) * 64;
    const int bi = bh / NH, hi = bh % NH;
    const unsigned short* Kh = Kg + (size_t)bh * S_LEN * HD;
    const unsigned short* Vh = Vtg + (size_t)bh * HD * S_LEN;

    // Q fragments from Q^T [B,H,d,S] (once per block; pre-scaled).
    // a0/a1 serve as the B-fragment of Q^T in the swapped QK^T (identical
    // lane data to the A-fragment of Q).
    bf16x8 a0, a1;
    {
        const unsigned short* Qt = Qtg + (size_t)bh * HD * S_LEN + (q0 + w*16 + lq);
#pragma unroll
        for (int j = 0; j < 8; j++) {
            a0[j] = (short)Qt[(size_t)(quad*8 + j) * S_LEN];
            a1[j] = (short)Qt[(size_t)(quad*8 + j + 32) * S_LEN];
        }
    }

    // mask -> LDS, pre-scaled by log2(e)
    {
        const float4* mb4 = (const float4*)(maskg + (size_t)bi * S_LEN);
#pragma unroll
        for (int i = 0; i < 2; i++) {
            int idx = i * 256 + tid;
            float4 v = mb4[idx];
            float4 sv; sv.x = v.x*L2E; sv.y = v.y*L2E; sv.z = v.z*L2E; sv.w = v.w*L2E;
            ((float4*)mkL)[idx] = sv;
        }
    }

    bf16x8 ones;
#pragma unroll
    for (int i = 0; i < 8; i++) ones[i] = (short)0x3F80;   // bf16 1.0

    const int srow = l >> 3, schunk = ((l & 7) ^ (l >> 3)) * 8;
    const unsigned short* kga = Kh + (size_t)(w*16 + srow) * HD + schunk;
    const unsigned short* vga = Vh + (size_t)(w*16 + srow) * S_LEN + schunk;

    const int c0 = ((quad)     ^ (lq & 7)) * 8;
    const int c1 = ((4 + quad) ^ (lq & 7)) * 8;
    // P store geometry: quad/2 selects even/odd chunk parity, quad&1 selects
    // lower/upper half of the 8-elem chunk. Full chunk index XOR'd per-g.
    const int pqh = quad >> 1;
    const int po  = (quad & 1) * 4;
    const int pe  = lq & 7;

    f32x4 zero = {0.f, 0.f, 0.f, 0.f};
    f32x4 o[4], lsum = zero;
#pragma unroll
    for (int ng = 0; ng < 4; ng++) o[ng] = zero;

    auto stage = [&](int buf, int kt) {
#pragma unroll
        for (int i = 0; i < 2; i++) {
            GLL16(kga + (size_t)kt*64*HD + i*8*HD, &Ks[buf][w*16 + i*8][0]);
            GLL16(vga + kt*64 + (size_t)i*8*S_LEN, &Vt[buf][w*16 + i*8][0]);
        }
    };

    auto compute = [&](int buf, int kt) {
        const int kk = kt * 64;

        // ---- swapped QK^T: st[g][r] = S^T[kk+g*16+quad*4+r][q0+w*16+lq] ----
        f32x4 st[4];
#pragma unroll
        for (int g = 0; g < 4; g++) {
            bf16x8 b0 = *(const bf16x8*)&Ks[buf][g*16 + lq][c0];
            bf16x8 b1 = *(const bf16x8*)&Ks[buf][g*16 + lq][c1];
            f32x4 z = __builtin_amdgcn_mfma_f32_16x16x32_bf16(b0, a0, zero, 0, 0, 0);
            st[g]   = __builtin_amdgcn_mfma_f32_16x16x32_bf16(b1, a1, z,    0, 0, 0);
        }

        // ---- softmax numerator, lane-local: 4 consecutive k per g ----
#pragma unroll
        for (int g = 0; g < 4; g++) {
            const f32x4 mmg = *(const f32x4*)&mkL[kk + g*16 + quad*4];
            float p0 = exp2f(st[g][0] + mmg[0]);
            float p1 = exp2f(st[g][1] + mmg[1]);
            float p2 = exp2f(st[g][2] + mmg[2]);
            float p3 = exp2f(st[g][3] + mmg[3]);
            uint2 pr;
            pr.x = cvtpk(p0, p1);
            pr.y = cvtpk(p2, p3);
            // FIX: swizzle the FULL chunk index (g*2 + quad/2) ^ (lq&7)
            *(uint2*)&Ps[w][lq][((g*2 + pqh) ^ pe) * 8 + po] = pr;
        }

        // ---- P reload as A-fragment (wave-private, same swizzle as Ks) ----
        bf16x8 pa0 = *(const bf16x8*)&Ps[w][lq][c0];
        bf16x8 pa1 = *(const bf16x8*)&Ps[w][lq][c1];

        lsum = __builtin_amdgcn_mfma_f32_16x16x32_bf16(pa0, ones, lsum, 0, 0, 0);
        lsum = __builtin_amdgcn_mfma_f32_16x16x32_bf16(pa1, ones, lsum, 0, 0, 0);

        // ---- PV ----
#pragma unroll
        for (int ng = 0; ng < 4; ng++) {
            bf16x8 v0 = *(const bf16x8*)&Vt[buf][ng*16 + lq][c0];
            bf16x8 v1 = *(const bf16x8*)&Vt[buf][ng*16 + lq][c1];
            f32x4 t = __builtin_amdgcn_mfma_f32_16x16x32_bf16(pa0, v0, o[ng], 0, 0, 0);
            o[ng]   = __builtin_amdgcn_mfma_f32_16x16x32_bf16(pa1, v1, t,     0, 0, 0);
        }
    };

    stage(0, 0);
    __syncthreads();   // drains vmcnt (tile 0) + mask/LDS visible

    for (int kt = 0; kt < S_LEN / 64; kt += 2) {
        stage(1, kt + 1);
        compute(0, kt);
        __syncthreads();
        if (kt + 2 < S_LEN / 64) stage(0, kt + 2);
        compute(1, kt + 1);
        __syncthreads();
    }

    // epilogue: out[bi, q, hi*64 + d] fp32
#pragma unroll
    for (int r = 0; r < 4; r++) {
        const float inv = 1.0f / lsum[r];
        const int row = q0 + w*16 + quad*4 + r;
#pragma unroll
        for (int ng = 0; ng < 4; ng++)
            out[((size_t)(bi * S_LEN + row)) * HID + hi*HD + ng*16 + lq] = o[ng][r] * inv;
    }
}

extern "C" void kernel_launch(void* const* d_in, const int* in_sizes, int n_in,
                              void* d_out, int out_size, void* d_ws, size_t ws_size,
                              hipStream_t stream) {
    const float* X    = (const float*)d_in[0];
    const float* mask = (const float*)d_in[1];
    const float* Wq   = (const float*)d_in[2];
    const float* bq   = (const float*)d_in[3];
    const float* Wk   = (const float*)d_in[4];
    const float* bk   = (const float*)d_in[5];
    const float* Wv   = (const float*)d_in[6];
    const float* bv   = (const float*)d_in[7];
    float* out = (float*)d_out;

    const size_t per = (size_t)BATCH * NH * S_LEN * HD;  // 3,145,728
    unsigned short* qb = (unsigned short*)d_ws;           // Q^T [B,H,64,S]
    unsigned short* kb = qb + per;                        // K   [B,H,S,64]
    unsigned short* vb = kb + per;                        // V^T [B,H,64,S]
    unsigned short* xb = vb + per;                        // 4096*768
    unsigned short* wt = xb + (size_t)4096 * GK;          // 2304*768

    prep_kernel<<<4800, 256, 0, stream>>>(X, Wq, Wk, Wv, xb, wt);

    dim3 ggrid(2304 / 64, 4096 / 128);    // (36, 32) = 1152 blocks
    gemm_qkv<<<ggrid, 256, 0, stream>>>(xb, wt, bq, bk, bv, qb, kb, vb);

    dim3 agrid(S_LEN / 64, BATCH * NH);   // (32, 24) = 768 blocks = 3/CU
    attn_kernel<<<agrid, 256, 0, stream>>>(qb, kb, vb, mask, out);
}

// Round 3
// 155.709 us; speedup vs baseline: 1.0435x; 1.0294x over previous
//
#include <hip/hip_runtime.h>

#define S_LEN 2048
#define HID   768
#define NH    12
#define HD    64
#define BATCH 2
#define GK    768   // GEMM K dim
#define L2E   1.44269504088896340736f
#define QSCL  (0.125f * L2E)

typedef __attribute__((ext_vector_type(8))) short bf16x8;
typedef __attribute__((ext_vector_type(4))) float f32x4;
typedef __attribute__((ext_vector_type(4))) short s16x4;
typedef __attribute__((ext_vector_type(8))) short s16x8;

// fp32 -> bf16 RNE (prep only)
__device__ __forceinline__ unsigned short f2bf(float f) {
    union { float f; unsigned int u; } v; v.f = f;
    unsigned int r = v.u + 0x7fffu + ((v.u >> 16) & 1u);
    return (unsigned short)(r >> 16);
}
// fp32 -> bf16 round-half-up: 1 VALU + hi-half extract (<=1 ulp vs RNE)
__device__ __forceinline__ unsigned short f2bf_hu(float f) {
    union { float f; unsigned int u; } v; v.f = f;
    return (unsigned short)((v.u + 0x8000u) >> 16);
}

// two fp32 -> packed bf16 pair (RNE), 1 VALU (no builtin on gfx950).
__device__ __forceinline__ unsigned int cvtpk(float a, float b) {
    unsigned int r;
    asm("v_cvt_pk_bf16_f32 %0, %1, %2" : "=v"(r) : "v"(a), "v"(b));
    return r;
}

// raw exp2: skip libm guard. Builtin preferred (compiler models TRANS hazard).
#if __has_builtin(__builtin_amdgcn_exp2f)
#define EXP2(x) __builtin_amdgcn_exp2f(x)
#else
__device__ __forceinline__ float EXP2(float x) {
    float r;
    asm volatile("v_exp_f32 %0, %1\n\ts_nop 0" : "=v"(r) : "v"(x));
    return r;
}
#endif

// async global->LDS, 16B per lane, dest = wave-uniform base + lane*16
#define GLL16(gp, lp) __builtin_amdgcn_global_load_lds( \
    (const __attribute__((address_space(1))) unsigned int*)(gp), \
    (__attribute__((address_space(3))) unsigned int*)(lp), 16, 0, 0)

// XOR-swizzle (kept): 16B chunk (row, c) lives at LDS chunk c ^ (row&7);
// applied via the per-lane *global source* pointer, zero per-tile cost.

// ---------------------------------------------------------------------------
// Merged prep: blocks [0,3072) convert X fp32->bf16; [3072,4800) transpose+
// convert Wq|Wk|Wv -> Wt; [4800,4804) pre-scale mask by log2(e) into ws.
// Wq rows and later bq are pre-scaled by QSCL.
// ---------------------------------------------------------------------------
__global__ __launch_bounds__(256) void prep_kernel(
    const float* __restrict__ X, const float* __restrict__ Wq,
    const float* __restrict__ Wk, const float* __restrict__ Wv,
    const float* __restrict__ maskg,
    unsigned short* __restrict__ Xb, unsigned short* __restrict__ Wt,
    float* __restrict__ wsm) {
    __shared__ float T[32][33];
    int bid = blockIdx.x;
    if (bid >= 4800) {                   // mask pre-scale: 1024 float4
        int idx = (bid - 4800) * 256 + threadIdx.x;
        float4 v = ((const float4*)maskg)[idx];
        float4 s; s.x = v.x*L2E; s.y = v.y*L2E; s.z = v.z*L2E; s.w = v.w*L2E;
        ((float4*)wsm)[idx] = s;
        return;
    }
    if (bid < 3072) {
        int id = bid * 256 + threadIdx.x;   // one float4 per thread
        float4 v = ((const float4*)X)[id];
        s16x4 o; o[0] = (short)f2bf(v.x); o[1] = (short)f2bf(v.y);
        o[2] = (short)f2bf(v.z); o[3] = (short)f2bf(v.w);
        ((s16x4*)Xb)[id] = o;
        return;
    }
    int t2 = bid - 3072;
    int mat = t2 / 576, t = t2 % 576;
    int tk = t / 24, tn = t % 24;
    const float* W = (mat == 0) ? Wq : (mat == 1) ? Wk : Wv;
    const float scl = (mat == 0) ? QSCL : 1.0f;
    int r  = threadIdx.x >> 3;
    int c4 = (threadIdx.x & 7) * 4;
    float4 v = *(const float4*)&W[(size_t)(tk*32 + r) * GK + tn*32 + c4];
    T[c4+0][r] = v.x; T[c4+1][r] = v.y; T[c4+2][r] = v.z; T[c4+3][r] = v.w;
    __syncthreads();
    s16x4 o;
    o[0] = (short)f2bf(T[r][c4+0] * scl); o[1] = (short)f2bf(T[r][c4+1] * scl);
    o[2] = (short)f2bf(T[r][c4+2] * scl); o[3] = (short)f2bf(T[r][c4+3] * scl);
    *(s16x4*)&Wt[(size_t)(mat*768 + tn*32 + r) * GK + tk*32 + c4] = o;
}

// ---------------------------------------------------------------------------
// Fused QKV GEMM, bf16 MFMA 16x16x32, 128(M)x128(N) tile (m97 shape), BK=64,
// 576 blocks (XCD-swizzled, 576=8*72). global_load_lds width=16 staging,
// XOR-swizzled LDS. 4 waves = 2x2, each 64x64 output (4x4 frags).
// Q -> TRANSPOSED [B,H,64,S] (pre-scaled), K -> [B,H,S,64], V -> [B,H,64,S].
// ---------------------------------------------------------------------------
__global__ __launch_bounds__(256) void gemm_qkv(
    const unsigned short* __restrict__ Xb, const unsigned short* __restrict__ Wt,
    const float* __restrict__ bq, const float* __restrict__ bk,
    const float* __restrict__ bv,
    unsigned short* __restrict__ qb, unsigned short* __restrict__ kb,
    unsigned short* __restrict__ vb) {
    __shared__ __align__(16) unsigned short As[128][64];
    __shared__ __align__(16) unsigned short Bs[128][64];

    const int tid = threadIdx.x;
    // bijective XCD swizzle: 576 = 8 XCDs x 72
    const int wgid = blockIdx.y * gridDim.x + blockIdx.x;
    const int virt = (wgid & 7) * 72 + (wgid >> 3);
    const int bm = (virt / 18) * 128;
    const int bn = (virt % 18) * 128;
    const int w = tid >> 6, l = tid & 63, quad = l >> 4, lq = l & 15;
    const int wx = w & 1, wy = w >> 1;

    const int srow = l >> 3, schunk = ((l & 7) ^ (l >> 3)) * 8;
    const unsigned short* aga = Xb + (size_t)(bm + w*32 + srow) * GK + schunk;
    const unsigned short* bga = Wt + (size_t)(bn + w*32 + srow) * GK + schunk;

    const int c0 = ((quad)     ^ (lq & 7)) * 8;
    const int c1 = ((4 + quad) ^ (lq & 7)) * 8;

    f32x4 zero = {0.f, 0.f, 0.f, 0.f};
    f32x4 acc[4][4];
#pragma unroll
    for (int mi = 0; mi < 4; mi++)
#pragma unroll
        for (int ni = 0; ni < 4; ni++) acc[mi][ni] = zero;

    for (int k0 = 0; k0 < GK; k0 += 64) {
        __syncthreads();
#pragma unroll
        for (int i = 0; i < 4; i++) {
            GLL16(aga + k0 + i*8*GK, &As[w*32 + i*8][0]);
            GLL16(bga + k0 + i*8*GK, &Bs[w*32 + i*8][0]);
        }
        __syncthreads();
#pragma unroll
        for (int kh = 0; kh < 2; kh++) {
            const int cc = kh ? c1 : c0;
            bf16x8 a[4], b[4];
#pragma unroll
            for (int mi = 0; mi < 4; mi++)
                a[mi] = *(const bf16x8*)&As[wy*64 + mi*16 + lq][cc];
#pragma unroll
            for (int ni = 0; ni < 4; ni++)
                b[ni] = *(const bf16x8*)&Bs[wx*64 + ni*16 + lq][cc];
#pragma unroll
            for (int mi = 0; mi < 4; mi++)
#pragma unroll
                for (int ni = 0; ni < 4; ni++)
                    acc[mi][ni] = __builtin_amdgcn_mfma_f32_16x16x32_bf16(
                        a[mi], b[ni], acc[mi][ni], 0, 0, 0);
        }
    }

    const int mat = bn / 768;   // 768 = 6*128: block never straddles matrices
    const float* bias = (mat == 0) ? bq : (mat == 1) ? bk : bv;
    const float bscl = (mat == 0) ? QSCL : 1.0f;
    const int nbase = bn % 768;
#pragma unroll
    for (int ni = 0; ni < 4; ni++) {
        int hn = nbase + wx*64 + ni*16 + lq;
        float bval = bias[hn] * bscl;
        int h = hn >> 6, d = hn & 63;
#pragma unroll
        for (int mi = 0; mi < 4; mi++) {
            int m0 = bm + wy*64 + mi*16 + quad*4;
            int b_ = m0 >> 11, s0 = m0 & 2047;
            if (mat != 1) {
                // transposed [B,H,d,S]: 4 consecutive s -> one 8B store
                unsigned short* outp = (mat == 0) ? qb : vb;
                s16x4 pk;
#pragma unroll
                for (int r = 0; r < 4; r++) pk[r] = (short)f2bf_hu(acc[mi][ni][r] + bval);
                *(s16x4*)&outp[((size_t)((b_*NH + h) * HD + d)) * S_LEN + s0] = pk;
            } else {
                size_t base = ((size_t)((b_*NH + h) * S_LEN + s0)) * HD + d;
#pragma unroll
                for (int r = 0; r < 4; r++)
                    kb[base + (size_t)r * HD] = f2bf_hu(acc[mi][ni][r] + bval);
            }
        }
    }
}

// ---------------------------------------------------------------------------
// MFMA flash attention v8. Block = (b*h, 64 q-rows), 4 waves x 16 q-rows.
// vs v7b: mask LDS buffer removed (LDS 48->40KB => 4 blocks/CU, occ +33%);
// mask pre-scaled in prep, prefetched per-tile to regs, folded into QK^T as
// MFMA C-init (C[row=k][col=q] init = mask[k] -- kills 16 v_add/tile);
// raw v_exp2 (no libm guard). Swapped QK^T + cvt_pk + b64 P stores kept.
// LDS = 16K Ks + 16K Vt + 8K Ps = 40 KB.
// ---------------------------------------------------------------------------
__global__ __launch_bounds__(256, 4) void attn_kernel(
    const unsigned short* __restrict__ Qtg, const unsigned short* __restrict__ Kg,
    const unsigned short* __restrict__ Vtg, const float* __restrict__ wsm,
    float* __restrict__ out) {
    __shared__ __align__(16) unsigned short Ks[2][64][64];
    __shared__ __align__(16) unsigned short Vt[2][64][64];
    __shared__ __align__(16) unsigned short Ps[4][16][64];

    const int tid = threadIdx.x;
    const int w = tid >> 6, l = tid & 63, quad = l >> 4, lq = l & 15;

    // bijective XCD swizzle (768 = 8 x 96): each XCD owns 3 heads' q-blocks
    const int wgid = blockIdx.y * gridDim.x + blockIdx.x;
    const int virt = (wgid & 7) * 96 + (wgid >> 3);
    const int bh = virt >> 5;
    const int q0 = (virt & 31) * 64;
    const int bi = bh / NH, hi = bh % NH;
    const unsigned short* Kh = Kg + (size_t)bh * S_LEN * HD;
    const unsigned short* Vh = Vtg + (size_t)bh * HD * S_LEN;
    const float* wsmb = wsm + (size_t)bi * S_LEN;

    // Q fragments from Q^T [B,H,d,S] (once per block; pre-scaled by QSCL).
    bf16x8 a0, a1;
    {
        const unsigned short* Qt = Qtg + (size_t)bh * HD * S_LEN + (q0 + w*16 + lq);
#pragma unroll
        for (int j = 0; j < 8; j++) {
            a0[j] = (short)Qt[(size_t)(quad*8 + j) * S_LEN];
            a1[j] = (short)Qt[(size_t)(quad*8 + j + 32) * S_LEN];
        }
    }

    bf16x8 ones;
#pragma unroll
    for (int i = 0; i < 8; i++) ones[i] = (short)0x3F80;   // bf16 1.0

    const int srow = l >> 3, schunk = ((l & 7) ^ (l >> 3)) * 8;
    const unsigned short* kga = Kh + (size_t)(w*16 + srow) * HD + schunk;
    const unsigned short* vga = Vh + (size_t)(w*16 + srow) * S_LEN + schunk;

    const int c0 = ((quad)     ^ (lq & 7)) * 8;
    const int c1 = ((4 + quad) ^ (lq & 7)) * 8;
    // P store geometry (r2, verified): chunk (g*2 + quad/2) ^ (lq&7), half po
    const int pqh = quad >> 1;
    const int po  = (quad & 1) * 4;
    const int pe  = lq & 7;

    f32x4 zero = {0.f, 0.f, 0.f, 0.f};
    f32x4 o[4], lsum = zero;
#pragma unroll
    for (int ng = 0; ng < 4; ng++) o[ng] = zero;

    auto stage = [&](int buf, int kt) {
#pragma unroll
        for (int i = 0; i < 2; i++) {
            GLL16(kga + (size_t)kt*64*HD + i*8*HD, &Ks[buf][w*16 + i*8][0]);
            GLL16(vga + kt*64 + (size_t)i*8*S_LEN, &Vt[buf][w*16 + i*8][0]);
        }
    };

    auto ldm = [&](f32x4* dst, int kt) {
#pragma unroll
        for (int g = 0; g < 4; g++)
            dst[g] = *(const f32x4*)&wsmb[kt*64 + g*16 + quad*4];
    };

    auto compute = [&](int buf, const f32x4* mk) {
        // ---- swapped QK^T, mask as C-init: st[g][r] = S^T + mask ----
        f32x4 st[4];
#pragma unroll
        for (int g = 0; g < 4; g++) {
            bf16x8 b0 = *(const bf16x8*)&Ks[buf][g*16 + lq][c0];
            bf16x8 b1 = *(const bf16x8*)&Ks[buf][g*16 + lq][c1];
            f32x4 z = __builtin_amdgcn_mfma_f32_16x16x32_bf16(b0, a0, mk[g], 0, 0, 0);
            st[g]   = __builtin_amdgcn_mfma_f32_16x16x32_bf16(b1, a1, z,     0, 0, 0);
        }

        // ---- softmax numerator, lane-local: 4 consecutive k per g ----
#pragma unroll
        for (int g = 0; g < 4; g++) {
            float p0 = EXP2(st[g][0]);
            float p1 = EXP2(st[g][1]);
            float p2 = EXP2(st[g][2]);
            float p3 = EXP2(st[g][3]);
            uint2 pr;
            pr.x = cvtpk(p0, p1);
            pr.y = cvtpk(p2, p3);
            *(uint2*)&Ps[w][lq][((g*2 + pqh) ^ pe) * 8 + po] = pr;
        }

        // ---- P reload as A-fragment (wave-private, same swizzle as Ks) ----
        bf16x8 pa0 = *(const bf16x8*)&Ps[w][lq][c0];
        bf16x8 pa1 = *(const bf16x8*)&Ps[w][lq][c1];

        lsum = __builtin_amdgcn_mfma_f32_16x16x32_bf16(pa0, ones, lsum, 0, 0, 0);
        lsum = __builtin_amdgcn_mfma_f32_16x16x32_bf16(pa1, ones, lsum, 0, 0, 0);

        // ---- PV ----
#pragma unroll
        for (int ng = 0; ng < 4; ng++) {
            bf16x8 v0 = *(const bf16x8*)&Vt[buf][ng*16 + lq][c0];
            bf16x8 v1 = *(const bf16x8*)&Vt[buf][ng*16 + lq][c1];
            f32x4 t = __builtin_amdgcn_mfma_f32_16x16x32_bf16(pa0, v0, o[ng], 0, 0, 0);
            o[ng]   = __builtin_amdgcn_mfma_f32_16x16x32_bf16(pa1, v1, t,     0, 0, 0);
        }
    };

    f32x4 mkA[4], mkB[4];
    ldm(mkA, 0);
    stage(0, 0);
    __syncthreads();   // drains vmcnt (tile 0)

    for (int kt = 0; kt < S_LEN / 64; kt += 2) {
        stage(1, kt + 1); ldm(mkB, kt + 1);
        compute(0, mkA);
        __syncthreads();
        if (kt + 2 < S_LEN / 64) { stage(0, kt + 2); ldm(mkA, kt + 2); }
        compute(1, mkB);
        __syncthreads();
    }

    // epilogue: out[bi, q, hi*64 + d] fp32
#pragma unroll
    for (int r = 0; r < 4; r++) {
        const float inv = 1.0f / lsum[r];
        const int row = q0 + w*16 + quad*4 + r;
#pragma unroll
        for (int ng = 0; ng < 4; ng++)
            out[((size_t)(bi * S_LEN + row)) * HID + hi*HD + ng*16 + lq] = o[ng][r] * inv;
    }
}

extern "C" void kernel_launch(void* const* d_in, const int* in_sizes, int n_in,
                              void* d_out, int out_size, void* d_ws, size_t ws_size,
                              hipStream_t stream) {
    const float* X    = (const float*)d_in[0];
    const float* mask = (const float*)d_in[1];
    const float* Wq   = (const float*)d_in[2];
    const float* bq   = (const float*)d_in[3];
    const float* Wk   = (const float*)d_in[4];
    const float* bk   = (const float*)d_in[5];
    const float* Wv   = (const float*)d_in[6];
    const float* bv   = (const float*)d_in[7];
    float* out = (float*)d_out;

    const size_t per = (size_t)BATCH * NH * S_LEN * HD;  // 3,145,728
    unsigned short* qb = (unsigned short*)d_ws;           // Q^T [B,H,64,S]
    unsigned short* kb = qb + per;                        // K   [B,H,S,64]
    unsigned short* vb = kb + per;                        // V^T [B,H,64,S]
    unsigned short* xb = vb + per;                        // 4096*768
    unsigned short* wt = xb + (size_t)4096 * GK;          // 2304*768
    float* wsm = (float*)(wt + (size_t)2304 * GK);        // 2*2048 f32 (mask*log2e)

    prep_kernel<<<4804, 256, 0, stream>>>(X, Wq, Wk, Wv, mask, xb, wt, wsm);

    dim3 ggrid(18, 32);                   // 576 blocks, 128x128 tiles
    gemm_qkv<<<ggrid, 256, 0, stream>>>(xb, wt, bq, bk, bv, qb, kb, vb);

    dim3 agrid(S_LEN / 64, BATCH * NH);   // (32, 24) = 768 blocks = 4/CU max
    attn_kernel<<<agrid, 256, 0, stream>>>(qb, kb, vb, wsm, out);
}

// Round 4
// 147.726 us; speedup vs baseline: 1.0999x; 1.0540x over previous
//
#include <hip/hip_runtime.h>

#define S_LEN 2048
#define HID   768
#define NH    12
#define HD    64
#define BATCH 2
#define GK    768   // GEMM K dim
#define L2E   1.44269504088896340736f
#define QSCL  (0.125f * L2E)

typedef __attribute__((ext_vector_type(8))) short bf16x8;
typedef __attribute__((ext_vector_type(4))) float f32x4;
typedef __attribute__((ext_vector_type(4))) short s16x4;
typedef __attribute__((ext_vector_type(8))) short s16x8;

// fp32 -> bf16 RNE (prep only)
__device__ __forceinline__ unsigned short f2bf(float f) {
    union { float f; unsigned int u; } v; v.f = f;
    unsigned int r = v.u + 0x7fffu + ((v.u >> 16) & 1u);
    return (unsigned short)(r >> 16);
}
// fp32 -> bf16 round-half-up: 1 VALU + hi-half extract (<=1 ulp vs RNE)
__device__ __forceinline__ unsigned short f2bf_hu(float f) {
    union { float f; unsigned int u; } v; v.f = f;
    return (unsigned short)((v.u + 0x8000u) >> 16);
}

// two fp32 -> packed bf16 pair (RNE), 1 VALU (no builtin on gfx950).
__device__ __forceinline__ unsigned int cvtpk(float a, float b) {
    unsigned int r;
    asm("v_cvt_pk_bf16_f32 %0, %1, %2" : "=v"(r) : "v"(a), "v"(b));
    return r;
}

// raw exp2: skip libm guard. Builtin preferred (compiler models TRANS hazard).
#if __has_builtin(__builtin_amdgcn_exp2f)
#define EXP2(x) __builtin_amdgcn_exp2f(x)
#else
__device__ __forceinline__ float EXP2(float x) {
    float r;
    asm volatile("v_exp_f32 %0, %1\n\ts_nop 0" : "=v"(r) : "v"(x));
    return r;
}
#endif

// async global->LDS, 16B per lane, dest = wave-uniform base + lane*16
#define GLL16(gp, lp) __builtin_amdgcn_global_load_lds( \
    (const __attribute__((address_space(1))) unsigned int*)(gp), \
    (__attribute__((address_space(3))) unsigned int*)(lp), 16, 0, 0)

// ---------------------------------------------------------------------------
// Merged prep: blocks [0,3072) convert X fp32->bf16; [3072,4800) transpose+
// convert Wq|Wk|Wv -> Wt; [4800,4804) pre-scale mask by log2(e) into ws.
// Wq rows and later bq are pre-scaled by QSCL.
// ---------------------------------------------------------------------------
__global__ __launch_bounds__(256) void prep_kernel(
    const float* __restrict__ X, const float* __restrict__ Wq,
    const float* __restrict__ Wk, const float* __restrict__ Wv,
    const float* __restrict__ maskg,
    unsigned short* __restrict__ Xb, unsigned short* __restrict__ Wt,
    float* __restrict__ wsm) {
    __shared__ float T[32][33];
    int bid = blockIdx.x;
    if (bid >= 4800) {                   // mask pre-scale: 1024 float4
        int idx = (bid - 4800) * 256 + threadIdx.x;
        float4 v = ((const float4*)maskg)[idx];
        float4 s; s.x = v.x*L2E; s.y = v.y*L2E; s.z = v.z*L2E; s.w = v.w*L2E;
        ((float4*)wsm)[idx] = s;
        return;
    }
    if (bid < 3072) {
        int id = bid * 256 + threadIdx.x;   // one float4 per thread
        float4 v = ((const float4*)X)[id];
        s16x4 o; o[0] = (short)f2bf(v.x); o[1] = (short)f2bf(v.y);
        o[2] = (short)f2bf(v.z); o[3] = (short)f2bf(v.w);
        ((s16x4*)Xb)[id] = o;
        return;
    }
    int t2 = bid - 3072;
    int mat = t2 / 576, t = t2 % 576;
    int tk = t / 24, tn = t % 24;
    const float* W = (mat == 0) ? Wq : (mat == 1) ? Wk : Wv;
    const float scl = (mat == 0) ? QSCL : 1.0f;
    int r  = threadIdx.x >> 3;
    int c4 = (threadIdx.x & 7) * 4;
    float4 v = *(const float4*)&W[(size_t)(tk*32 + r) * GK + tn*32 + c4];
    T[c4+0][r] = v.x; T[c4+1][r] = v.y; T[c4+2][r] = v.z; T[c4+3][r] = v.w;
    __syncthreads();
    s16x4 o;
    o[0] = (short)f2bf(T[r][c4+0] * scl); o[1] = (short)f2bf(T[r][c4+1] * scl);
    o[2] = (short)f2bf(T[r][c4+2] * scl); o[3] = (short)f2bf(T[r][c4+3] * scl);
    *(s16x4*)&Wt[(size_t)(mat*768 + tn*32 + r) * GK + tk*32 + c4] = o;
}

// ---------------------------------------------------------------------------
// Fused QKV GEMM (r2 128x64 shape restored + XCD swizzle). bf16 MFMA
// 16x16x32, 128(M)x64(N) tile, BK=64, 1152 blocks = 8 XCDs x 144.
// global_load_lds width=16 staging, XOR-swizzled LDS.
// Q -> TRANSPOSED [B,H,64,S] (pre-scaled), K -> [B,H,S,64], V -> [B,H,64,S].
// ---------------------------------------------------------------------------
__global__ __launch_bounds__(256) void gemm_qkv(
    const unsigned short* __restrict__ Xb, const unsigned short* __restrict__ Wt,
    const float* __restrict__ bq, const float* __restrict__ bk,
    const float* __restrict__ bv,
    unsigned short* __restrict__ qb, unsigned short* __restrict__ kb,
    unsigned short* __restrict__ vb) {
    __shared__ __align__(16) unsigned short As[128][64];
    __shared__ __align__(16) unsigned short Bs[64][64];

    const int tid = threadIdx.x;
    // bijective XCD swizzle: 1152 = 8 XCDs x 144 (4 M-tiles x 36 N-tiles each)
    const int wgid = blockIdx.y * gridDim.x + blockIdx.x;
    const int virt = (wgid & 7) * 144 + (wgid >> 3);
    const int bm = (virt / 36) * 128;
    const int bn = (virt % 36) * 64;
    const int w = tid >> 6, l = tid & 63, quad = l >> 4, lq = l & 15;
    const int wx = w & 1, wy = w >> 1;

    const int srow = l >> 3, schunk = ((l & 7) ^ (l >> 3)) * 8;
    const unsigned short* aga = Xb + (size_t)(bm + w*32 + srow) * GK + schunk;
    const unsigned short* bga = Wt + (size_t)(bn + w*16 + srow) * GK + schunk;

    const int c0 = ((quad)     ^ (lq & 7)) * 8;
    const int c1 = ((4 + quad) ^ (lq & 7)) * 8;

    f32x4 zero = {0.f, 0.f, 0.f, 0.f};
    f32x4 acc[4][2];
#pragma unroll
    for (int mi = 0; mi < 4; mi++)
#pragma unroll
        for (int ni = 0; ni < 2; ni++) acc[mi][ni] = zero;

    for (int k0 = 0; k0 < GK; k0 += 64) {
        __syncthreads();
#pragma unroll
        for (int i = 0; i < 4; i++)
            GLL16(aga + k0 + i*8*GK, &As[w*32 + i*8][0]);
#pragma unroll
        for (int i = 0; i < 2; i++)
            GLL16(bga + k0 + i*8*GK, &Bs[w*16 + i*8][0]);
        __syncthreads();
#pragma unroll
        for (int kh = 0; kh < 2; kh++) {
            const int cc = kh ? c1 : c0;
            bf16x8 a[4], b[2];
#pragma unroll
            for (int mi = 0; mi < 4; mi++)
                a[mi] = *(const bf16x8*)&As[wy*64 + mi*16 + lq][cc];
#pragma unroll
            for (int ni = 0; ni < 2; ni++)
                b[ni] = *(const bf16x8*)&Bs[wx*32 + ni*16 + lq][cc];
#pragma unroll
            for (int mi = 0; mi < 4; mi++)
#pragma unroll
                for (int ni = 0; ni < 2; ni++)
                    acc[mi][ni] = __builtin_amdgcn_mfma_f32_16x16x32_bf16(
                        a[mi], b[ni], acc[mi][ni], 0, 0, 0);
        }
    }

    const int mat = bn / 768;   // block never straddles matrices
    const float* bias = (mat == 0) ? bq : (mat == 1) ? bk : bv;
    const float bscl = (mat == 0) ? QSCL : 1.0f;
    const int nbase = bn % 768;
#pragma unroll
    for (int ni = 0; ni < 2; ni++) {
        int hn = nbase + wx*32 + ni*16 + lq;
        float bval = bias[hn] * bscl;
        int h = hn >> 6, d = hn & 63;
#pragma unroll
        for (int mi = 0; mi < 4; mi++) {
            int m0 = bm + wy*64 + mi*16 + quad*4;
            int b_ = m0 >> 11, s0 = m0 & 2047;
            if (mat != 1) {
                // transposed [B,H,d,S]: 4 consecutive s -> one 8B store
                unsigned short* outp = (mat == 0) ? qb : vb;
                s16x4 pk;
#pragma unroll
                for (int r = 0; r < 4; r++) pk[r] = (short)f2bf_hu(acc[mi][ni][r] + bval);
                *(s16x4*)&outp[((size_t)((b_*NH + h) * HD + d)) * S_LEN + s0] = pk;
            } else {
                size_t base = ((size_t)((b_*NH + h) * S_LEN + s0)) * HD + d;
#pragma unroll
                for (int r = 0; r < 4; r++)
                    kb[base + (size_t)r * HD] = f2bf_hu(acc[mi][ni][r] + bval);
            }
        }
    }
}

// ---------------------------------------------------------------------------
// MFMA flash attention v9. Block = (b*h, 64 q-rows), 4 waves x 16 q-rows.
// vs v8: P LDS round-trip ELIMINATED. The K fragment is loaded with
// permuted rows rho(m) = (m>>2)*8 + (m&3) (+4/+32/+36 across 4 calls), so
// the swapped-QK^T output rows (m = quad*4+r) land at k = quad*8+r —
// exactly the PV A-fragment's lane layout. pa0/pa1 are built in-register
// (16 exp2 + 8 cvtpk), no ds_write/ds_read, no cross-lane ops.
// K uses its own LDS swizzle fK(row)=(row&3)|((row>>3&1)<<2) so permuted
// fragment reads stay 2-way (free); V keeps the old (row&7) swizzle.
// Mask C-init re-indexed to k = quad*8 + {0..3,4..7,32..35,36..39}.
// LDS = 16K Ks + 16K Vt = 32 KB.
// ---------------------------------------------------------------------------
__global__ __launch_bounds__(256, 4) void attn_kernel(
    const unsigned short* __restrict__ Qtg, const unsigned short* __restrict__ Kg,
    const unsigned short* __restrict__ Vtg, const float* __restrict__ wsm,
    float* __restrict__ out) {
    __shared__ __align__(16) unsigned short Ks[2][64][64];
    __shared__ __align__(16) unsigned short Vt[2][64][64];

    const int tid = threadIdx.x;
    const int w = tid >> 6, l = tid & 63, quad = l >> 4, lq = l & 15;

    // bijective XCD swizzle (768 = 8 x 96): each XCD owns 3 heads' q-blocks
    const int wgid = blockIdx.y * gridDim.x + blockIdx.x;
    const int virt = (wgid & 7) * 96 + (wgid >> 3);
    const int bh = virt >> 5;
    const int q0 = (virt & 31) * 64;
    const int bi = bh / NH, hi = bh % NH;
    const unsigned short* Kh = Kg + (size_t)bh * S_LEN * HD;
    const unsigned short* Vh = Vtg + (size_t)bh * HD * S_LEN;
    const float* wsmb = wsm + (size_t)bi * S_LEN;

    // Q fragments from Q^T [B,H,d,S] (once per block; pre-scaled by QSCL).
    bf16x8 a0, a1;
    {
        const unsigned short* Qt = Qtg + (size_t)bh * HD * S_LEN + (q0 + w*16 + lq);
#pragma unroll
        for (int j = 0; j < 8; j++) {
            a0[j] = (short)Qt[(size_t)(quad*8 + j) * S_LEN];
            a1[j] = (short)Qt[(size_t)(quad*8 + j + 32) * S_LEN];
        }
    }

    bf16x8 ones;
#pragma unroll
    for (int i = 0; i < 8; i++) ones[i] = (short)0x3F80;   // bf16 1.0

    const int srow = l >> 3;
    // V staging (old swizzle: chunk ^ (row&7))
    const int svchunk = ((l & 7) ^ (l >> 3)) * 8;
    const unsigned short* vga = Vh + (size_t)(w*16 + srow) * S_LEN + svchunk;
    // K staging (new swizzle fK(row) = (row&3) | ((row>>3 & 1)<<2));
    // dest rows w*16+i*8+srow: fK = (srow&3) | (i<<2)
    const int ckK = ((l & 7) ^ ((l >> 3) & 3)) * 8;
    const unsigned short* kga0 = Kh + (size_t)(w*16 + srow) * HD + ckK;
    const unsigned short* kga1 = Kh + (size_t)(w*16 + 8 + srow) * HD + (ckK ^ 32);

    // Vt read slots (old pattern)
    const int c0 = ((quad)     ^ (lq & 7)) * 8;
    const int c1 = ((4 + quad) ^ (lq & 7)) * 8;
    // K fragment read: permuted rows rho = krA + {0,4,32,36}; slots via fK
    const int fk  = (lq & 3) | (((lq >> 2) & 1) << 2);
    const int kc0 = (quad ^ fk) * 8;
    const int kc1 = kc0 ^ 32;
    const int krA = (lq >> 2) * 8 + (lq & 3);

    f32x4 zero = {0.f, 0.f, 0.f, 0.f};
    f32x4 o[4], lsum = zero;
#pragma unroll
    for (int ng = 0; ng < 4; ng++) o[ng] = zero;

    auto stage = [&](int buf, int kt) {
        GLL16(kga0 + (size_t)kt*64*HD, &Ks[buf][w*16][0]);
        GLL16(kga1 + (size_t)kt*64*HD, &Ks[buf][w*16 + 8][0]);
        GLL16(vga + kt*64,                   &Vt[buf][w*16][0]);
        GLL16(vga + kt*64 + (size_t)8*S_LEN, &Vt[buf][w*16 + 8][0]);
    };

    // per-lane mask (QK^T C-init): k = quad*8 + {0..3, 4..7, 32..35, 36..39}
    auto ldm = [&](f32x4* dst, int kt) {
        const float* mb = wsmb + kt*64 + quad*8;
        dst[0] = *(const f32x4*)(mb);
        dst[1] = *(const f32x4*)(mb + 4);
        dst[2] = *(const f32x4*)(mb + 32);
        dst[3] = *(const f32x4*)(mb + 36);
    };

    auto compute = [&](int buf, const f32x4* mk) {
        // ---- swapped QK^T with permuted K rows; mask as C-init ----
        // call c: rows rho = krA + roff[c]; st[c][r] = S^T[k=quad*8+off][q=lq]
        f32x4 st[4];
#pragma unroll
        for (int c = 0; c < 4; c++) {
            const int roff = (c & 1) * 4 + (c >> 1) * 32;
            bf16x8 b0 = *(const bf16x8*)&Ks[buf][krA + roff][kc0];
            bf16x8 b1 = *(const bf16x8*)&Ks[buf][krA + roff][kc1];
            f32x4 z = __builtin_amdgcn_mfma_f32_16x16x32_bf16(b0, a0, mk[c], 0, 0, 0);
            st[c]   = __builtin_amdgcn_mfma_f32_16x16x32_bf16(b1, a1, z,     0, 0, 0);
        }

        // ---- softmax numerator fully in-register: exp2 + cvt_pk ----
        union PU { unsigned int d[4]; bf16x8 v; } p0u, p1u;
#pragma unroll
        for (int c = 0; c < 2; c++) {
            float e0 = EXP2(st[c][0]), e1 = EXP2(st[c][1]);
            float e2 = EXP2(st[c][2]), e3 = EXP2(st[c][3]);
            p0u.d[c*2]   = cvtpk(e0, e1);
            p0u.d[c*2+1] = cvtpk(e2, e3);
        }
#pragma unroll
        for (int c = 0; c < 2; c++) {
            float e0 = EXP2(st[2+c][0]), e1 = EXP2(st[2+c][1]);
            float e2 = EXP2(st[2+c][2]), e3 = EXP2(st[2+c][3]);
            p1u.d[c*2]   = cvtpk(e0, e1);
            p1u.d[c*2+1] = cvtpk(e2, e3);
        }
        bf16x8 pa0 = p0u.v, pa1 = p1u.v;

        lsum = __builtin_amdgcn_mfma_f32_16x16x32_bf16(pa0, ones, lsum, 0, 0, 0);
        lsum = __builtin_amdgcn_mfma_f32_16x16x32_bf16(pa1, ones, lsum, 0, 0, 0);

        // ---- PV ----
#pragma unroll
        for (int ng = 0; ng < 4; ng++) {
            bf16x8 v0 = *(const bf16x8*)&Vt[buf][ng*16 + lq][c0];
            bf16x8 v1 = *(const bf16x8*)&Vt[buf][ng*16 + lq][c1];
            f32x4 t = __builtin_amdgcn_mfma_f32_16x16x32_bf16(pa0, v0, o[ng], 0, 0, 0);
            o[ng]   = __builtin_amdgcn_mfma_f32_16x16x32_bf16(pa1, v1, t,     0, 0, 0);
        }
    };

    f32x4 mkA[4], mkB[4];
    ldm(mkA, 0);
    stage(0, 0);
    __syncthreads();   // drains vmcnt (tile 0)

    for (int kt = 0; kt < S_LEN / 64; kt += 2) {
        stage(1, kt + 1); ldm(mkB, kt + 1);
        compute(0, mkA);
        __syncthreads();
        if (kt + 2 < S_LEN / 64) { stage(0, kt + 2); ldm(mkA, kt + 2); }
        compute(1, mkB);
        __syncthreads();
    }

    // epilogue: out[bi, q, hi*64 + d] fp32
#pragma unroll
    for (int r = 0; r < 4; r++) {
        const float inv = 1.0f / lsum[r];
        const int row = q0 + w*16 + quad*4 + r;
#pragma unroll
        for (int ng = 0; ng < 4; ng++)
            out[((size_t)(bi * S_LEN + row)) * HID + hi*HD + ng*16 + lq] = o[ng][r] * inv;
    }
}

extern "C" void kernel_launch(void* const* d_in, const int* in_sizes, int n_in,
                              void* d_out, int out_size, void* d_ws, size_t ws_size,
                              hipStream_t stream) {
    const float* X    = (const float*)d_in[0];
    const float* mask = (const float*)d_in[1];
    const float* Wq   = (const float*)d_in[2];
    const float* bq   = (const float*)d_in[3];
    const float* Wk   = (const float*)d_in[4];
    const float* bk   = (const float*)d_in[5];
    const float* Wv   = (const float*)d_in[6];
    const float* bv   = (const float*)d_in[7];
    float* out = (float*)d_out;

    const size_t per = (size_t)BATCH * NH * S_LEN * HD;  // 3,145,728
    unsigned short* qb = (unsigned short*)d_ws;           // Q^T [B,H,64,S]
    unsigned short* kb = qb + per;                        // K   [B,H,S,64]
    unsigned short* vb = kb + per;                        // V^T [B,H,64,S]
    unsigned short* xb = vb + per;                        // 4096*768
    unsigned short* wt = xb + (size_t)4096 * GK;          // 2304*768
    float* wsm = (float*)(wt + (size_t)2304 * GK);        // 2*2048 f32 (mask*log2e)

    prep_kernel<<<4804, 256, 0, stream>>>(X, Wq, Wk, Wv, mask, xb, wt, wsm);

    dim3 ggrid(36, 32);                   // 1152 blocks, 128x64 tiles
    gemm_qkv<<<ggrid, 256, 0, stream>>>(xb, wt, bq, bk, bv, qb, kb, vb);

    dim3 agrid(S_LEN / 64, BATCH * NH);   // (32, 24) = 768 blocks = 3/CU
    attn_kernel<<<agrid, 256, 0, stream>>>(qb, kb, vb, wsm, out);
}